// Round 4
// baseline (660.034 us; speedup 1.0000x reference)
//
#include <hip/hip_runtime.h>
#include <cstddef>

#define T_LEN 512
#define IN_D 8
#define H 32
#define NBATCH 16        // batches per WG (MFMA M)
#define NT 128           // 2 waves: wave d owns unit-half d, ALL 4 gates
#define LOG2E 1.44269504088896341f

typedef __attribute__((ext_vector_type(8))) short bf16x8;
typedef __attribute__((ext_vector_type(4))) float f32x4;
typedef __attribute__((ext_vector_type(4))) unsigned u32x4;

__device__ __forceinline__ float fexp2(float v) { return __builtin_amdgcn_exp2f(v); }
__device__ __forceinline__ float frcp(float v)  { return __builtin_amdgcn_rcpf(v); }
__device__ __forceinline__ unsigned short f2bf(float f) {   // RNE fp32->bf16 (setup only)
    unsigned u = __builtin_bit_cast(unsigned, f);
    u += 0x7FFF + ((u >> 16) & 1);
    return (unsigned short)(u >> 16);
}
__device__ __forceinline__ float bf2f(unsigned short b) {
    unsigned u = ((unsigned)b) << 16;
    return __builtin_bit_cast(float, u);
}
__device__ __forceinline__ float ubits(unsigned u) { return __builtin_bit_cast(float, u); }
// packed RNE fp32x2 -> bf16x2 (arg0 -> low16, arg1 -> high16)
__device__ __forceinline__ unsigned cvt_pk_bf16(float lo, float hi) {
    unsigned r;
    asm("v_cvt_pk_bf16_f32 %0, %1, %2" : "=v"(r) : "v"(lo), "v"(hi));
    return r;
}

// LDS-only barrier: no vmcnt drain (global x prefetch stays in flight).
#define WG_BARRIER() asm volatile("s_waitcnt lgkmcnt(0)\n\ts_barrier" ::: "memory")

// Gate-fused re-tiling: wave d computes ALL 4 gate-tiles (g,d) for the WG's 16
// batches -> the 4 gate values of cell (batch=4q+rg, unit=cc+16d) live in the
// SAME lane at the SAME reg index. Activation + c-update + h are pure per-lane
// register math: the G exchange and barrier-1 are GONE; cs lives in registers
// across all 512 steps. Per step: 2 b128 h-reads, 12 recurrence MFMAs (hi/lo),
// in-place XC refill (4 MFMAs, x loaded per-lane from global, 2-step prefetch,
// no LDS staging), 16 sigmoid + 4 tanh per lane, 8 b16 h-writes, ONE barrier.
// h pitch 40 shorts: b16 writes exactly 2-way banks, b128 reads 16B-aligned.
__global__ void __launch_bounds__(NT, 1) lstm_fused(
    const float* __restrict__ x, const float* __restrict__ W_ih,
    const float* __restrict__ W_hh, const float* __restrict__ b_ih,
    const float* __restrict__ b_hh, const float* __restrict__ W_fc,
    const float* __restrict__ b_fc, float* __restrict__ out)
{
    __shared__ __align__(16) unsigned short hhi[NBATCH][40];   // 1280 B, pi-order cols
    __shared__ __align__(16) unsigned short hlo[NBATCH][40];   // 1280 B

    const int tix  = threadIdx.x;
    const int d    = tix >> 6;          // unit half (wave id)
    const int lane = tix & 63;
    const int q    = lane >> 4;         // k-quad (A/B) / row-group (C)
    const int cc   = lane & 15;         // A row (batch) / B col (unit-in-tile)

    // ---- static B fragments: 4 gate-tiles (g,d), kk pre-folded ----
    bf16x8 Bh[4], Bl[4], Bx[4];
    f32x4 biasv[4];
    #pragma unroll
    for (int g = 0; g < 4; ++g) {
        const float kkg = (g == 2) ? 2.f * LOG2E : -LOG2E;
        const int r = 32 * g + 16 * d + cc;           // global gate-row
        #pragma unroll
        for (int j = 0; j < 8; ++j) {
            const int p = 8 * q + j;                  // k position (pi-order)
            const int u = 16 * (p & 1) + (p >> 1);    // unit index
            const float ws = kkg * W_hh[r * H + u];
            const unsigned short whi = f2bf(ws);
            Bh[g][j] = (short)whi;
            Bl[g][j] = (short)f2bf(ws - bf2f(whi));
            if (q == 3) {
                Bx[g][j] = 0;                          // zero k-quad
            } else {
                const float wsx = kkg * W_ih[r * IN_D + j];
                const unsigned short xwh = f2bf(wsx);
                // q=0,1 multiply x_hi/x_lo by W_hi; q=2 multiplies x_hi by W_lo
                Bx[g][j] = (q == 2) ? (short)f2bf(wsx - bf2f(xwh)) : (short)xwh;
            }
        }
        const float b = kkg * (b_ih[r] + b_hh[r]);
        biasv[g][0] = b; biasv[g][1] = b; biasv[g][2] = b; biasv[g][3] = b;
    }

    // ---- per-lane x A-frag builder: lane loads x[batch=cc][t][0..7] itself ----
    const float* xp = x + (size_t)(blockIdx.x * NBATCH + cc) * (size_t)(T_LEN * IN_D);
    auto build = [&](float4 a, float4 b) -> bf16x8 {
        const unsigned w0 = cvt_pk_bf16(a.x, a.y);
        const unsigned w1 = cvt_pk_bf16(a.z, a.w);
        const unsigned w2 = cvt_pk_bf16(b.x, b.y);
        const unsigned w3 = cvt_pk_bf16(b.z, b.w);
        unsigned s0 = w0, s1 = w1, s2 = w2, s3 = w3;
        if (q == 1) {                                  // x_lo quad
            s0 = cvt_pk_bf16(a.x - ubits(w0 << 16), a.y - ubits(w0 & 0xffff0000u));
            s1 = cvt_pk_bf16(a.z - ubits(w1 << 16), a.w - ubits(w1 & 0xffff0000u));
            s2 = cvt_pk_bf16(b.x - ubits(w2 << 16), b.y - ubits(w2 & 0xffff0000u));
            s3 = cvt_pk_bf16(b.z - ubits(w3 << 16), b.w - ubits(w3 & 0xffff0000u));
        }
        if (q == 3) { s0 = 0; s1 = 0; s2 = 0; s3 = 0; }
        u32x4 r_ = { s0, s1, s2, s3 };
        return __builtin_bit_cast(bf16x8, r_);
    };

    // ---- init: zero h (h0 = 0) ----
    for (int i = tix; i < NBATCH * 40 / 2; i += NT) {
        ((unsigned*)hhi)[i] = 0u;
        ((unsigned*)hlo)[i] = 0u;
    }
    __syncthreads();

    // ---- prologue: XC for t=0, prefetch x[1] ----
    f32x4 XC[4];
    {
        const float4 ta = *(const float4*)(xp + 0);
        const float4 tb = *(const float4*)(xp + 4);
        const bf16x8 fr = build(ta, tb);
        #pragma unroll
        for (int g = 0; g < 4; ++g)
            XC[g] = __builtin_amdgcn_mfma_f32_16x16x32_bf16(fr, Bx[g], biasv[g], 0, 0, 0);
    }
    float4 ra = *(const float4*)(xp + 8);
    float4 rb = *(const float4*)(xp + 12);

    float cs[4] = { 0.f, 0.f, 0.f, 0.f };
    float hfin[4] = { 0.f, 0.f, 0.f, 0.f };
    const float TWL = 2.f * LOG2E, FML = -4.f * LOG2E;

    for (int t = 0; t < T_LEN; ++t) {
        // ---- h A-frags + 12 MFMAs (acc starts at in-register XC) ----
        const bf16x8 A0 = *(const bf16x8*)&hhi[cc][8 * q];
        const bf16x8 A2 = *(const bf16x8*)&hlo[cc][8 * q];
        f32x4 C[4];
        #pragma unroll
        for (int g = 0; g < 4; ++g) {
            const f32x4 z = { 0.f, 0.f, 0.f, 0.f };
            f32x4 a1 = __builtin_amdgcn_mfma_f32_16x16x32_bf16(A0, Bh[g], XC[g], 0, 0, 0);
            f32x4 a2 = __builtin_amdgcn_mfma_f32_16x16x32_bf16(A2, Bh[g], z, 0, 0, 0);
            a2 = __builtin_amdgcn_mfma_f32_16x16x32_bf16(A0, Bl[g], a2, 0, 0, 0);
            C[g] = a1 + a2;
        }

        // ---- in-place XC refill for t+1 (XC[g] already consumed above) ----
        {
            const bf16x8 fr = build(ra, rb);
            #pragma unroll
            for (int g = 0; g < 4; ++g)
                XC[g] = __builtin_amdgcn_mfma_f32_16x16x32_bf16(fr, Bx[g], biasv[g], 0, 0, 0);
        }
        // ---- prefetch x[t+2] (clamped; stays in flight across the barrier) ----
        const int tn = (t + 2 < T_LEN) ? (t + 2) : (T_LEN - 1);
        ra = *(const float4*)(xp + (size_t)tn * IN_D);
        rb = *(const float4*)(xp + (size_t)tn * IN_D + 4);

        // ---- per-lane activation + c/h: 4 cells (batch 4q+j, unit cc+16d) ----
        #pragma unroll
        for (int j = 0; j < 4; ++j) {
            const float iv = frcp(1.f + fexp2(C[0][j]));
            const float fv = frcp(1.f + fexp2(C[1][j]));
            const float gv = TWL + FML * frcp(1.f + fexp2(C[2][j]));  // 2L*tanh(g)
            const float ov = frcp(1.f + fexp2(C[3][j]));
            cs[j] = fv * cs[j] + iv * gv;            // cs = 2L*c
            const float rr = frcp(1.f + fexp2(cs[j]));
            const float hv = ov - 2.f * ov * rr;     // o * tanh(c)
            hfin[j] = hv;
            const unsigned hw = cvt_pk_bf16(hv, hv);
            const float hl = hv - ubits(hw << 16);
            const unsigned lw = cvt_pk_bf16(hl, hl);
            hhi[4 * q + j][2 * cc + d] = (unsigned short)hw;   // pi col = 2cc+d
            hlo[4 * q + j][2 * cc + d] = (unsigned short)lw;
        }

        WG_BARRIER();               // the ONLY barrier per step
    }

    // ---- epilogue: out[b] = h_n . W_fc + b_fc ----
    if (tix < NBATCH) {
        float s = b_fc[0];
        #pragma unroll
        for (int p = 0; p < H; ++p) {
            const int u = 16 * (p & 1) + (p >> 1);
            s += (bf2f(hhi[tix][p]) + bf2f(hlo[tix][p])) * W_fc[u];
        }
        out[blockIdx.x * NBATCH + tix] = s;
    }
    (void)hfin;
}

extern "C" void kernel_launch(void* const* d_in, const int* in_sizes, int n_in,
                              void* d_out, int out_size, void* d_ws, size_t ws_size,
                              hipStream_t stream) {
    const float* x    = (const float*)d_in[0];
    const float* W_ih = (const float*)d_in[1];
    const float* W_hh = (const float*)d_in[2];
    const float* b_ih = (const float*)d_in[3];
    const float* b_hh = (const float*)d_in[4];
    const float* W_fc = (const float*)d_in[5];
    const float* b_fc = (const float*)d_in[6];
    float* out = (float*)d_out;
    const int Bn = in_sizes[0] / (T_LEN * IN_D);   // 8192
    lstm_fused<<<dim3(Bn / NBATCH), dim3(NT), 0, stream>>>(
        x, W_ih, W_hh, b_ih, b_hh, W_fc, b_fc, out);
}